// Round 5
// baseline (895.490 us; speedup 1.0000x reference)
//
#include <hip/hip_runtime.h>
#include <stdint.h>
#include <stddef.h>

#define S_LEN 1024
#define BATCH 8
#define EMB   1024
#define NHEAD 16
#define HDIM  64
#define FDIM  4096
#define NTOK  (S_LEN*BATCH)   // 8192

typedef unsigned short u16s;
typedef __attribute__((ext_vector_type(4))) float  f32x4;
typedef __attribute__((ext_vector_type(8))) u16s   u16x8;
typedef __attribute__((ext_vector_type(4))) u16s   u16x4;
typedef __attribute__((ext_vector_type(8))) __bf16 bf16x8;

__device__ __forceinline__ u16s f2bf(float f) {
  unsigned int x = __float_as_uint(f);
  return (u16s)((x + 0x7FFFu + ((x >> 16) & 1u)) >> 16);
}

__device__ __forceinline__ f32x4 mfma_bf16(u16x8 a, u16x8 b, f32x4 c) {
  return __builtin_amdgcn_mfma_f32_16x16x32_bf16(
      __builtin_bit_cast(bf16x8, a), __builtin_bit_cast(bf16x8, b), c, 0, 0, 0);
}

__device__ __forceinline__ void gload16(const void* g, void* l) {
  __builtin_amdgcn_global_load_lds(
      (const __attribute__((address_space(1))) unsigned int*)g,
      (__attribute__((address_space(3))) unsigned int*)l, 16, 0, 0);
}

#define VMCNT(n) asm volatile("s_waitcnt vmcnt(" #n ")" ::: "memory")

__device__ __forceinline__ void block_sync() {
  __builtin_amdgcn_sched_barrier(0);
  asm volatile("" ::: "memory");
  __builtin_amdgcn_s_barrier();
  asm volatile("" ::: "memory");
  __builtin_amdgcn_sched_barrier(0);
}

// ---------------- cast fp32 -> bf16 ----------------
__global__ __launch_bounds__(256) void cast_kernel(const float* __restrict__ in,
                                                   u16s* __restrict__ out, int n4) {
  int i = blockIdx.x * 256 + threadIdx.x;
  if (i < n4) {
    float4 v = ((const float4*)in)[i];
    u16x4 o;
    o[0] = f2bf(v.x); o[1] = f2bf(v.y); o[2] = f2bf(v.z); o[3] = f2bf(v.w);
    ((u16x4*)out)[i] = o;
  }
}

// ---------------- concat q/k/v biases into one 3072 vector ----------------
__global__ __launch_bounds__(256) void concat_bias_kernel(const float* __restrict__ a,
                                                          const float* __restrict__ b,
                                                          const float* __restrict__ c,
                                                          float* __restrict__ o) {
  int i = blockIdx.x * 256 + threadIdx.x;  // 0..3071
  o[i] = (i < 1024) ? a[i] : (i < 2048) ? b[i - 1024] : c[i - 2048];
}

// ---------------- z projections (B=8 rows) ----------------
__global__ __launch_bounds__(256) void zproj_kernel(const float* __restrict__ z,
                                                    const float* __restrict__ w,
                                                    const float* __restrict__ bias,
                                                    float* __restrict__ out) {
  const int o = blockIdx.x * 256 + threadIdx.x;   // 0..1023
  float acc[8] = {};
  const float* wr = w + (size_t)o * EMB;
  for (int e = 0; e < EMB; e += 4) {
    float4 wv = *(const float4*)(wr + e);
#pragma unroll
    for (int b = 0; b < 8; ++b) {
      float4 zv = *(const float4*)(z + b * EMB + e);
      acc[b] += zv.x * wv.x + zv.y * wv.y + zv.z * wv.z + zv.w * wv.w;
    }
  }
  float bb = bias[o];
#pragma unroll
  for (int b = 0; b < 8; ++b) out[b * EMB + o] = acc[b] + bb;
}

// ---------------- LayerNorm ----------------
template <int MODE>
__global__ __launch_bounds__(256) void ln_kernel(const float* __restrict__ y,
                                                 const float* __restrict__ gam,
                                                 const float* __restrict__ bet,
                                                 u16s* __restrict__ obf,
                                                 float* __restrict__ of) {
  const int row = blockIdx.x;
  const int t = threadIdx.x;
  const float* yr = y + (size_t)row * EMB;
  float4 v = ((const float4*)yr)[t];
  float s = v.x + v.y + v.z + v.w;
  float s2 = v.x * v.x + v.y * v.y + v.z * v.z + v.w * v.w;
#pragma unroll
  for (int m = 1; m < 64; m <<= 1) { s += __shfl_xor(s, m); s2 += __shfl_xor(s2, m); }
  __shared__ float red[8];
  const int wid = t >> 6, lane = t & 63;
  if (lane == 0) { red[wid] = s; red[4 + wid] = s2; }
  __syncthreads();
  s = red[0] + red[1] + red[2] + red[3];
  s2 = red[4] + red[5] + red[6] + red[7];
  float mu = s * (1.f / EMB);
  float var = s2 * (1.f / EMB) - mu * mu;
  float rs = rsqrtf(var + 1e-5f);
  float4 g = ((const float4*)gam)[t];
  float4 b = ((const float4*)bet)[t];
  float4 o;
  o.x = (v.x - mu) * rs * g.x + b.x;
  o.y = (v.y - mu) * rs * g.y + b.y;
  o.z = (v.z - mu) * rs * g.z + b.z;
  o.w = (v.w - mu) * rs * g.w + b.w;
  if constexpr (MODE == 0) {
    u16x4 p;
    p[0] = f2bf(o.x); p[1] = f2bf(o.y); p[2] = f2bf(o.z); p[3] = f2bf(o.w);
    ((u16x4*)(obf + (size_t)row * EMB))[t] = p;
    ((float4*)(of + (size_t)row * EMB))[t] = o;
  } else {
    ((float4*)(of + (size_t)row * EMB))[t] = o;
  }
}

// ---------------- GEMM 256-N pipelined: C = A(MxK) * B(NxK)^T + bias --------
// Tile BM x 256 (BM = 128*BMT), BK=32, 8 waves (2Mx4N), per-wave (BM/2)x64.
// 3 LDS buffers, stage tile t+2 while computing tile t -> counted vmcnt, no
// drain-to-0 in main loop (raw s_barrier + manual s_waitcnt). LDS is
// chunk-major [k-chunk][row] (16B chunks) -> ds_read_b128 is 2-way = free.
// global_load_lds dest stays linear; the per-lane GLOBAL src is permuted.
enum { EPI_QKV3 = 0, EPI_RELU = 1, EPI_RES = 2, EPI_GATE = 3 };

template <int BMT, int EPI>
__global__ __launch_bounds__(512, 2) void gemm256(const u16s* __restrict__ A,
                                                  const u16s* __restrict__ Bw,
                                                  const float* __restrict__ bias,
                                                  void* __restrict__ out,
                                                  const float* __restrict__ res,
                                                  const float* __restrict__ zg,
                                                  const float* __restrict__ zv,
                                                  int M, int N, int K, float scale) {
  constexpr int BM = 128 * BMT;
  constexpr int MR = BM / 32;             // M frags per wave
  constexpr int LOG2BM = (BMT == 2) ? 8 : 7;
  __shared__ u16s As[3 * BM * 32];
  __shared__ u16s Bs[3 * 256 * 32];
  const int tid = threadIdx.x;
  const int wid = tid >> 6, lane = tid & 63;
  const int wm = wid >> 2, wn = wid & 3;
  const int l15 = lane & 15, l4 = lane >> 4;

  // XCD-chunked bijective swizzle (all our grids have nwg % 8 == 0)
  const int nwg = gridDim.x * gridDim.y;
  int lin = blockIdx.y * gridDim.x + blockIdx.x;
  if ((nwg & 7) == 0) lin = (lin & 7) * (nwg >> 3) + (lin >> 3);
  const int bm0 = (lin % gridDim.x) * BM;
  const int bn0 = (lin / gridDim.x) * 256;

  const int wbase = tid & ~63;  // wid*64 (wave-uniform LDS chunk base)

  auto stage = [&](int kt, int buf) {
#pragma unroll
    for (int ii = 0; ii < BMT; ++ii) {
      const int d = ii * 512 + tid;           // chunk index 0..BM*4-1
      const int row = d & (BM - 1);
      const int c = d >> LOG2BM;
      gload16(A + (size_t)(bm0 + row) * K + kt * 32 + c * 8,
              As + ((size_t)buf * (BM * 32)) + (size_t)(ii * 512 + wbase) * 8);
    }
#pragma unroll
    for (int ii = 0; ii < 2; ++ii) {
      const int d = ii * 512 + tid;           // chunk index 0..1023
      const int row = d & 255;
      const int c = d >> 8;
      gload16(Bw + (size_t)(bn0 + row) * K + kt * 32 + c * 8,
              Bs + ((size_t)buf * 8192) + (size_t)(ii * 512 + wbase) * 8);
    }
  };

  f32x4 acc[MR][4] = {};
  const int nkt = K >> 5;
  stage(0, 0);
  stage(1, 1);
  if constexpr (BMT == 2) VMCNT(4); else VMCNT(3);   // tile0 landed, tile1 in flight
  block_sync();

  int buf = 0;
  for (int t = 0; t < nkt; ++t) {
    if (t + 2 < nkt) stage(t + 2, (t + 2) % 3);      // buffer last read at t-1: safe
    const u16s* Ab = As + (size_t)buf * (BM * 32);
    const u16s* Bb = Bs + (size_t)buf * 8192;
    u16x8 af[MR], bfr[4];
#pragma unroll
    for (int i = 0; i < MR; ++i)
      af[i] = *(const u16x8*)(Ab + (size_t)((l4 << LOG2BM) + wm * (BM / 2) + i * 16 + l15) * 8);
#pragma unroll
    for (int j = 0; j < 4; ++j)
      bfr[j] = *(const u16x8*)(Bb + (size_t)(l4 * 256 + wn * 64 + j * 16 + l15) * 8);
    __builtin_amdgcn_s_setprio(1);
#pragma unroll
    for (int i = 0; i < MR; ++i)
#pragma unroll
      for (int j = 0; j < 4; ++j)
        acc[i][j] = mfma_bf16(af[i], bfr[j], acc[i][j]);
    __builtin_amdgcn_s_setprio(0);
    if (t + 2 < nkt) {
      if constexpr (BMT == 2) VMCNT(4); else VMCNT(3);  // t+1 landed; t+2 in flight
    } else {
      VMCNT(0);                                          // tail drain
    }
    block_sync();
    buf = (buf + 1 == 3) ? 0 : buf + 1;
  }

  float* outf = (float*)out;
  u16s* outb = (u16s*)out;
#pragma unroll
  for (int j = 0; j < 4; ++j) {
    const int gc = bn0 + wn * 64 + j * 16 + l15;
    const float bv = bias[gc];
#pragma unroll
    for (int i = 0; i < MR; ++i) {
      const int gr0 = bm0 + wm * (BM / 2) + i * 16 + l4 * 4;
#pragma unroll
      for (int r = 0; r < 4; ++r) {
        const int gr = gr0 + r;
        float v = acc[i][j][r] + bv;
        if constexpr (EPI == EPI_QKV3) {
          // columns 0..1023 -> Q (scaled), 1024..2047 -> K, 2048..3071 -> V^T
          const int which = gc >> 10, col = gc & 1023;
          const int srow = gr >> 3, b = gr & 7, h = col >> 6, d = col & 63;
          if (which == 0)
            outb[(size_t)(b * 16 + h) * 65536 + srow * 64 + d] = f2bf(v * scale);
          else if (which == 1)
            outb[8388608 + (size_t)(b * 16 + h) * 65536 + srow * 64 + d] = f2bf(v);
          else
            outb[16777216 + ((size_t)(b * 16 + h) * 64 + d) * 1024 + srow] = f2bf(v);
        } else if constexpr (EPI == EPI_RELU) {
          outb[(size_t)gr * N + gc] = f2bf(fmaxf(v, 0.f));
        } else if constexpr (EPI == EPI_RES) {
          outf[(size_t)gr * N + gc] = v + res[(size_t)gr * N + gc];
        } else {  // EPI_GATE
          const float lin2 = v + zg[(gr & 7) * EMB + gc];
          const float gate = 1.f / (1.f + __expf(-lin2));
          outf[(size_t)gr * EMB + gc] =
              res[(size_t)gr * EMB + gc] + gate * zv[(gr & 7) * EMB + gc];
        }
      }
    }
  }
}

// ---------------- causal flash attention (LDS-staged, load-balanced) --------
__global__ __launch_bounds__(256) void attn_kernel(const u16s* __restrict__ Q,
                                                   const u16s* __restrict__ K,
                                                   const u16s* __restrict__ VT,
                                                   u16s* __restrict__ O) {
  __shared__ u16s Ks[32 * 72];
  __shared__ u16s Vs[64 * 40];
  __shared__ u16s Pl[4][16 * 40];
  const int p = blockIdx.x, bh = blockIdx.y;
  const int tid = threadIdx.x;
  const int wid = tid >> 6, lane = tid & 63;
  const int l15 = lane & 15, l4 = lane >> 4;
  const size_t hoff = (size_t)bh * (S_LEN * HDIM);
  const u16s* Qb = Q + hoff;
  const u16s* Kb = K + hoff;
  const u16s* Vb = VT + hoff;   // [64][1024]
  u16s* Pw = Pl[wid];
  const int b = bh >> 4, h = bh & 15;

  const int kr = tid >> 3, kc = (tid & 7) * 8;   // K: row 0..31, col 0..56
  const int vr = tid >> 2, vc = (tid & 3) * 8;   // V: row 0..63, col 0..24

  for (int half = 0; half < 2; ++half) {
    const int qt = half ? (15 - p) : p;
    const int qrow = qt * 64 + wid * 16 + l15;
    const u16x8 qf0 = *(const u16x8*)(Qb + qrow * 64 + l4 * 8);
    const u16x8 qf1 = *(const u16x8*)(Qb + qrow * 64 + 32 + l4 * 8);
    f32x4 oa[4] = {};
    float mrun = -1e30f, lsum = 0.f;
    const int nkt = 2 * qt + 2;

    u16x8 kreg = *(const u16x8*)(Kb + (size_t)kr * 64 + kc);
    u16x8 vreg = *(const u16x8*)(Vb + (size_t)vr * 1024 + vc);

    for (int kt = 0; kt < nkt; ++kt) {
      __syncthreads();
      *(u16x8*)(Ks + kr * 72 + kc) = kreg;
      *(u16x8*)(Vs + vr * 40 + vc) = vreg;
      __syncthreads();
      if (kt + 1 < nkt) {
        kreg = *(const u16x8*)(Kb + (size_t)((kt + 1) * 32 + kr) * 64 + kc);
        vreg = *(const u16x8*)(Vb + (size_t)vr * 1024 + (kt + 1) * 32 + vc);
      }
      const int kbase = kt * 32;
      f32x4 sc0 = {0.f, 0.f, 0.f, 0.f}, sc1 = {0.f, 0.f, 0.f, 0.f};
      {
        u16x8 kf00 = *(const u16x8*)(Ks + l15 * 72 + l4 * 8);
        u16x8 kf01 = *(const u16x8*)(Ks + l15 * 72 + 32 + l4 * 8);
        u16x8 kf10 = *(const u16x8*)(Ks + (16 + l15) * 72 + l4 * 8);
        u16x8 kf11 = *(const u16x8*)(Ks + (16 + l15) * 72 + 32 + l4 * 8);
        __builtin_amdgcn_s_setprio(1);
        sc0 = mfma_bf16(kf00, qf0, sc0);
        sc0 = mfma_bf16(kf01, qf1, sc0);
        sc1 = mfma_bf16(kf10, qf0, sc1);
        sc1 = mfma_bf16(kf11, qf1, sc1);
        __builtin_amdgcn_s_setprio(0);
      }
      u16x8 vf[4];
#pragma unroll
      for (int df = 0; df < 4; ++df)
        vf[df] = *(const u16x8*)(Vs + (df * 16 + l15) * 40 + l4 * 8);

      float sv[8];
      float pmax = -1e30f;
#pragma unroll
      for (int r = 0; r < 4; ++r) {
        const int kg0 = kbase + l4 * 4 + r;
        const int kg1 = kbase + 16 + l4 * 4 + r;
        const float s0 = (kg0 <= qrow) ? sc0[r] : -1e9f;
        const float s1 = (kg1 <= qrow) ? sc1[r] : -1e9f;
        sv[r] = s0; sv[4 + r] = s1;
        pmax = fmaxf(pmax, fmaxf(s0, s1));
      }
      pmax = fmaxf(pmax, __shfl_xor(pmax, 16));
      pmax = fmaxf(pmax, __shfl_xor(pmax, 32));
      const float mnew = fmaxf(mrun, pmax);
      const float fsc = __expf(mrun - mnew);
      float psum = 0.f;
#pragma unroll
      for (int i = 0; i < 8; ++i) { float pv = __expf(sv[i] - mnew); sv[i] = pv; psum += pv; }
      psum += __shfl_xor(psum, 16);
      psum += __shfl_xor(psum, 32);
      lsum = lsum * fsc + psum;
      mrun = mnew;
#pragma unroll
      for (int df = 0; df < 4; ++df) oa[df] *= fsc;

      u16x4 pk0, pk1;
#pragma unroll
      for (int r = 0; r < 4; ++r) { pk0[r] = f2bf(sv[r]); pk1[r] = f2bf(sv[4 + r]); }
      *(u16x4*)(Pw + l15 * 40 + l4 * 4) = pk0;
      *(u16x4*)(Pw + l15 * 40 + 16 + l4 * 4) = pk1;
      asm volatile("s_waitcnt lgkmcnt(0)" ::: "memory");
      const u16x8 pf = *(const u16x8*)(Pw + l15 * 40 + l4 * 8);
      __builtin_amdgcn_s_setprio(1);
#pragma unroll
      for (int df = 0; df < 4; ++df)
        oa[df] = mfma_bf16(vf[df], pf, oa[df]);
      __builtin_amdgcn_s_setprio(0);
    }
    const float inv = 1.f / lsum;
    u16s* orow = O + ((size_t)qrow * 8 + b) * EMB + h * 64;
#pragma unroll
    for (int df = 0; df < 4; ++df)
#pragma unroll
      for (int r = 0; r < 4; ++r)
        orow[df * 16 + l4 * 4 + r] = f2bf(oa[df][r] * inv);
  }
}

// ---------------- driver ----------------
extern "C" void kernel_launch(void* const* d_in, const int* in_sizes, int n_in,
                              void* d_out, int out_size, void* d_ws, size_t ws_size,
                              hipStream_t stream) {
  const float* x = (const float*)d_in[0];
  const float* z = (const float*)d_in[1];
  const float* wq = (const float*)d_in[2];  const float* bq = (const float*)d_in[3];
  const float* wk = (const float*)d_in[4];  const float* bk = (const float*)d_in[5];
  const float* wv = (const float*)d_in[6];  const float* bv = (const float*)d_in[7];
  const float* wo = (const float*)d_in[8];  const float* bo = (const float*)d_in[9];
  const float* ln1g = (const float*)d_in[10]; const float* ln1b = (const float*)d_in[11];
  const float* pghw = (const float*)d_in[12]; const float* pghb = (const float*)d_in[13];
  const float* pgzw = (const float*)d_in[14]; const float* pgzb = (const float*)d_in[15];
  const float* pvw  = (const float*)d_in[16]; const float* pvb  = (const float*)d_in[17];
  const float* ln2g = (const float*)d_in[18]; const float* ln2b = (const float*)d_in[19];
  const float* fc1w = (const float*)d_in[20]; const float* fc1b = (const float*)d_in[21];
  const float* fc2w = (const float*)d_in[22]; const float* fc2b = (const float*)d_in[23];
  const float* ln3g = (const float*)d_in[24]; const float* ln3b = (const float*)d_in[25];

  char* ws = (char*)d_ws;
  size_t off = 0;
  auto alloc = [&](size_t bytes) -> char* {
    char* p = ws + off;
    off += (bytes + 255) & ~(size_t)255;
    return p;
  };

  u16s* bw_qkv = (u16s*)alloc(2u * 3145728);  // wq|wk|wv concat (3072x1024)
  u16s* bw_o = (u16s*)alloc(2u * 1048576);
  u16s* bw_g = (u16s*)alloc(2u * 1048576);
  u16s* bw_f1 = (u16s*)alloc(2u * 4194304);
  u16s* bw_f2 = (u16s*)alloc(2u * 4194304);
  u16s* xb = (u16s*)alloc(2u * 8388608);
  // qh, kh, vT, attnb are four contiguous 16MB buffers (the QKV3 epilogue
  // relies on qh+8388608 == kh, qh+16777216 == vT); hbuf (8192x4096 bf16 =
  // 64MB) aliases all four. vT is V pre-transposed per head: vT[bh][64][1024].
  u16s* qh = (u16s*)alloc(2u * 8388608);
  u16s* kh = (u16s*)alloc(2u * 8388608);
  u16s* vT = (u16s*)alloc(2u * 8388608);
  u16s* attnb = (u16s*)alloc(2u * 8388608);
  u16s* hbuf = qh;
  float* ybuf = (float*)alloc(4u * 8388608);
  u16s* x1b = (u16s*)alloc(2u * 8388608);
  float* x1f = (float*)alloc(4u * 8388608);
  float* zgb = (float*)alloc(4u * 8192);
  float* zvb = (float*)alloc(4u * 8192);
  float* bqkv = (float*)alloc(4u * 3072);
  (void)off; (void)ws_size; (void)in_sizes; (void)n_in; (void)out_size;
  (void)kh; (void)vT;

  auto cast = [&](const float* in, u16s* out, int n) {
    cast_kernel<<<n / 1024, 256, 0, stream>>>(in, out, n / 4);
  };
  cast(x, xb, 8388608);
  cast(wq, bw_qkv, 1048576);
  cast(wk, bw_qkv + 1048576, 1048576);
  cast(wv, bw_qkv + 2097152, 1048576);
  cast(wo, bw_o, 1048576);
  cast(pghw, bw_g, 1048576);
  cast(fc1w, bw_f1, 4194304);
  cast(fc2w, bw_f2, 4194304);
  concat_bias_kernel<<<12, 256, 0, stream>>>(bq, bk, bv, bqkv);

  // fused QKV projection (N=3072) with head-scatter epilogue
  gemm256<2, EPI_QKV3><<<dim3(32, 12), 512, 0, stream>>>(
      xb, bw_qkv, bqkv, qh, nullptr, nullptr, nullptr, NTOK, 3072, EMB, 0.125f);

  attn_kernel<<<dim3(8, 128), 256, 0, stream>>>(qh, kh, vT, attnb);

  // out-proj + residual(x) -> ybuf (f32), then LN1 -> x1 (bf16 + f32)
  gemm256<1, EPI_RES><<<dim3(64, 4), 512, 0, stream>>>(
      attnb, bw_o, bo, ybuf, x, nullptr, nullptr, NTOK, EMB, EMB, 1.f);
  ln_kernel<0><<<NTOK, 256, 0, stream>>>(ybuf, ln1g, ln1b, x1b, x1f);

  // gated fusion
  zproj_kernel<<<4, 256, 0, stream>>>(z, pgzw, pgzb, zgb);
  zproj_kernel<<<4, 256, 0, stream>>>(z, pvw, pvb, zvb);
  gemm256<1, EPI_GATE><<<dim3(64, 4), 512, 0, stream>>>(
      x1b, bw_g, pghb, ybuf, x1f, zgb, zvb, NTOK, EMB, EMB, 1.f);
  ln_kernel<0><<<NTOK, 256, 0, stream>>>(ybuf, ln2g, ln2b, x1b, x1f);  // x2 aliases x1

  // FFN
  gemm256<2, EPI_RELU><<<dim3(32, 16), 512, 0, stream>>>(
      x1b, bw_f1, fc1b, hbuf, nullptr, nullptr, nullptr, NTOK, FDIM, EMB, 1.f);
  gemm256<1, EPI_RES><<<dim3(64, 4), 512, 0, stream>>>(
      hbuf, bw_f2, fc2b, ybuf, x1f, nullptr, nullptr, NTOK, EMB, FDIM, 1.f);
  ln_kernel<1><<<NTOK, 256, 0, stream>>>(ybuf, ln3g, ln3b, nullptr, (float*)d_out);
}

// Round 6
// 733.624 us; speedup vs baseline: 1.2206x; 1.2206x over previous
//
#include <hip/hip_runtime.h>
#include <stdint.h>
#include <stddef.h>

#define S_LEN 1024
#define BATCH 8
#define EMB   1024
#define NHEAD 16
#define HDIM  64
#define FDIM  4096
#define NTOK  (S_LEN*BATCH)   // 8192

typedef unsigned short u16s;
typedef __attribute__((ext_vector_type(4))) float  f32x4;
typedef __attribute__((ext_vector_type(8))) u16s   u16x8;
typedef __attribute__((ext_vector_type(4))) u16s   u16x4;
typedef __attribute__((ext_vector_type(8))) __bf16 bf16x8;

__device__ __forceinline__ u16s f2bf(float f) {
  unsigned int x = __float_as_uint(f);
  return (u16s)((x + 0x7FFFu + ((x >> 16) & 1u)) >> 16);
}

__device__ __forceinline__ f32x4 mfma_bf16(u16x8 a, u16x8 b, f32x4 c) {
  return __builtin_amdgcn_mfma_f32_16x16x32_bf16(
      __builtin_bit_cast(bf16x8, a), __builtin_bit_cast(bf16x8, b), c, 0, 0, 0);
}

__device__ __forceinline__ void gload16(const void* g, void* l) {
  __builtin_amdgcn_global_load_lds(
      (const __attribute__((address_space(1))) unsigned int*)g,
      (__attribute__((address_space(3))) unsigned int*)l, 16, 0, 0);
}

// ---------------- cast fp32 -> bf16 ----------------
__global__ __launch_bounds__(256) void cast_kernel(const float* __restrict__ in,
                                                   u16s* __restrict__ out, int n4) {
  int i = blockIdx.x * 256 + threadIdx.x;
  if (i < n4) {
    float4 v = ((const float4*)in)[i];
    u16x4 o;
    o[0] = f2bf(v.x); o[1] = f2bf(v.y); o[2] = f2bf(v.z); o[3] = f2bf(v.w);
    ((u16x4*)out)[i] = o;
  }
}

// ---------------- concat q/k/v biases into one 3072 vector ----------------
__global__ __launch_bounds__(256) void concat_bias_kernel(const float* __restrict__ a,
                                                          const float* __restrict__ b,
                                                          const float* __restrict__ c,
                                                          float* __restrict__ o) {
  int i = blockIdx.x * 256 + threadIdx.x;  // 0..3071
  o[i] = (i < 1024) ? a[i] : (i < 2048) ? b[i - 1024] : c[i - 2048];
}

// ---------------- z projections (B=8 rows) ----------------
__global__ __launch_bounds__(256) void zproj_kernel(const float* __restrict__ z,
                                                    const float* __restrict__ w,
                                                    const float* __restrict__ bias,
                                                    float* __restrict__ out) {
  const int o = blockIdx.x * 256 + threadIdx.x;   // 0..1023
  float acc[8] = {};
  const float* wr = w + (size_t)o * EMB;
  for (int e = 0; e < EMB; e += 4) {
    float4 wv = *(const float4*)(wr + e);
#pragma unroll
    for (int b = 0; b < 8; ++b) {
      float4 zv = *(const float4*)(z + b * EMB + e);
      acc[b] += zv.x * wv.x + zv.y * wv.y + zv.z * wv.z + zv.w * wv.w;
    }
  }
  float bb = bias[o];
#pragma unroll
  for (int b = 0; b < 8; ++b) out[b * EMB + o] = acc[b] + bb;
}

// ---------------- LayerNorm ----------------
template <int MODE>
__global__ __launch_bounds__(256) void ln_kernel(const float* __restrict__ y,
                                                 const float* __restrict__ gam,
                                                 const float* __restrict__ bet,
                                                 u16s* __restrict__ obf,
                                                 float* __restrict__ of) {
  const int row = blockIdx.x;
  const int t = threadIdx.x;
  const float* yr = y + (size_t)row * EMB;
  float4 v = ((const float4*)yr)[t];
  float s = v.x + v.y + v.z + v.w;
  float s2 = v.x * v.x + v.y * v.y + v.z * v.z + v.w * v.w;
#pragma unroll
  for (int m = 1; m < 64; m <<= 1) { s += __shfl_xor(s, m); s2 += __shfl_xor(s2, m); }
  __shared__ float red[8];
  const int wid = t >> 6, lane = t & 63;
  if (lane == 0) { red[wid] = s; red[4 + wid] = s2; }
  __syncthreads();
  s = red[0] + red[1] + red[2] + red[3];
  s2 = red[4] + red[5] + red[6] + red[7];
  float mu = s * (1.f / EMB);
  float var = s2 * (1.f / EMB) - mu * mu;
  float rs = rsqrtf(var + 1e-5f);
  float4 g = ((const float4*)gam)[t];
  float4 b = ((const float4*)bet)[t];
  float4 o;
  o.x = (v.x - mu) * rs * g.x + b.x;
  o.y = (v.y - mu) * rs * g.y + b.y;
  o.z = (v.z - mu) * rs * g.z + b.z;
  o.w = (v.w - mu) * rs * g.w + b.w;
  if constexpr (MODE == 0) {
    u16x4 p;
    p[0] = f2bf(o.x); p[1] = f2bf(o.y); p[2] = f2bf(o.z); p[3] = f2bf(o.w);
    ((u16x4*)(obf + (size_t)row * EMB))[t] = p;
    ((float4*)(of + (size_t)row * EMB))[t] = o;
  } else {
    ((float4*)(of + (size_t)row * EMB))[t] = o;
  }
}

// ---------------- GEMM: C = A(MxK) * B(NxK)^T + bias, fused epilogues --------
// 128x128 tile, BK=64, 4 waves (2x2), each wave 4x4 frags of 16x16x32.
// LDS row-major [128][64] with XOR chunk swizzle: 16B chunk c of row r is
// stored at slot c^(r&7). ds_read_b128 then hits 8 distinct 16B slots across
// the 16 rows a fragment reads -> 2-way bank aliasing (free). Staging keeps
// global_load_lds with a LINEAR LDS dest; the XOR is applied to the GLOBAL
// source chunk index instead (both-sides rule): lane ell -> row=ell>>3,
// c = (ell&7)^(row&7). 8 lanes cover each row's contiguous 128B -> coalesced.
enum { EPI_QKV3 = 0, EPI_RELU = 1, EPI_RES = 2, EPI_GATE = 3 };

template <int EPI>
__global__ __launch_bounds__(256, 4) void gemm_nt(const u16s* __restrict__ A,
                                                  const u16s* __restrict__ Bw,
                                                  const float* __restrict__ bias,
                                                  void* __restrict__ out,
                                                  const float* __restrict__ res,
                                                  const float* __restrict__ zg,
                                                  const float* __restrict__ zv,
                                                  int M, int N, int K, float scale) {
  __shared__ u16s As[128 * 64];
  __shared__ u16s Bs[128 * 64];
  const int tid = threadIdx.x;
  const int wid = tid >> 6, lane = tid & 63;
  const int wm = wid >> 1, wn = wid & 1;
  const int l15 = lane & 15, l4 = lane >> 4;

  // bijective XCD-chunk swizzle (all grids here have nwg % 8 == 0)
  const int nwg = gridDim.x * gridDim.y;
  int lin = blockIdx.y * gridDim.x + blockIdx.x;
  lin = (lin & 7) * (nwg >> 3) + (lin >> 3);
  const int bm0 = (lin % gridDim.x) * 128;
  const int bn0 = (lin / gridDim.x) * 128;

  const int wbase = tid & ~63;
  // per-thread staging source (linear LDS chunk ell = ii*256 + tid)
  int srowA[4], scolA[4];
#pragma unroll
  for (int ii = 0; ii < 4; ++ii) {
    const int ell = ii * 256 + tid;
    const int row = ell >> 3;
    srowA[ii] = row;
    scolA[ii] = ((ell & 7) ^ (row & 7)) * 8;
  }

  f32x4 acc[4][4] = {};
  const int nkt = K >> 6;
  for (int kt = 0; kt < nkt; ++kt) {
#pragma unroll
    for (int ii = 0; ii < 4; ++ii) {
      gload16(A + (size_t)(bm0 + srowA[ii]) * K + kt * 64 + scolA[ii],
              As + (size_t)(ii * 256 + wbase) * 8);
      gload16(Bw + (size_t)(bn0 + srowA[ii]) * K + kt * 64 + scolA[ii],
              Bs + (size_t)(ii * 256 + wbase) * 8);
    }
    __syncthreads();
#pragma unroll
    for (int kk = 0; kk < 2; ++kk) {
      const int cs = kk * 4 + l4;
      u16x8 af[4], bfr[4];
#pragma unroll
      for (int i = 0; i < 4; ++i) {
        const int row = wm * 64 + i * 16 + l15;
        af[i] = *(const u16x8*)(As + row * 64 + (cs ^ (l15 & 7)) * 8);
      }
#pragma unroll
      for (int j = 0; j < 4; ++j) {
        const int row = wn * 64 + j * 16 + l15;
        bfr[j] = *(const u16x8*)(Bs + row * 64 + (cs ^ (l15 & 7)) * 8);
      }
      __builtin_amdgcn_s_setprio(1);
#pragma unroll
      for (int i = 0; i < 4; ++i)
#pragma unroll
        for (int j = 0; j < 4; ++j)
          acc[i][j] = mfma_bf16(af[i], bfr[j], acc[i][j]);
      __builtin_amdgcn_s_setprio(0);
    }
    __syncthreads();
  }

  float* outf = (float*)out;
  u16s* outb = (u16s*)out;
#pragma unroll
  for (int j = 0; j < 4; ++j) {
    const int gc = bn0 + wn * 64 + j * 16 + l15;
    const float bv = bias[gc];
#pragma unroll
    for (int i = 0; i < 4; ++i) {
      const int gr0 = bm0 + wm * 64 + i * 16 + l4 * 4;
#pragma unroll
      for (int r = 0; r < 4; ++r) {
        const int gr = gr0 + r;
        float v = acc[i][j][r] + bv;
        if constexpr (EPI == EPI_QKV3) {
          // columns 0..1023 -> Q (scaled), 1024..2047 -> K, 2048..3071 -> V^T
          const int which = gc >> 10, col = gc & 1023;
          const int srow = gr >> 3, b = gr & 7, h = col >> 6, d = col & 63;
          if (which == 0)
            outb[(size_t)(b * 16 + h) * 65536 + srow * 64 + d] = f2bf(v * scale);
          else if (which == 1)
            outb[8388608 + (size_t)(b * 16 + h) * 65536 + srow * 64 + d] = f2bf(v);
          else
            outb[16777216 + ((size_t)(b * 16 + h) * 64 + d) * 1024 + srow] = f2bf(v);
        } else if constexpr (EPI == EPI_RELU) {
          outb[(size_t)gr * N + gc] = f2bf(fmaxf(v, 0.f));
        } else if constexpr (EPI == EPI_RES) {
          outf[(size_t)gr * N + gc] = v + res[(size_t)gr * N + gc];
        } else {  // EPI_GATE
          const float lin2 = v + zg[(gr & 7) * EMB + gc];
          const float gate = 1.f / (1.f + __expf(-lin2));
          outf[(size_t)gr * EMB + gc] =
              res[(size_t)gr * EMB + gc] + gate * zv[(gr & 7) * EMB + gc];
        }
      }
    }
  }
}

// ---------------- causal flash attention (LDS-staged, load-balanced) --------
__global__ __launch_bounds__(256) void attn_kernel(const u16s* __restrict__ Q,
                                                   const u16s* __restrict__ K,
                                                   const u16s* __restrict__ VT,
                                                   u16s* __restrict__ O) {
  __shared__ u16s Ks[32 * 72];
  __shared__ u16s Vs[64 * 40];
  __shared__ u16s Pl[4][16 * 40];
  const int p = blockIdx.x, bh = blockIdx.y;
  const int tid = threadIdx.x;
  const int wid = tid >> 6, lane = tid & 63;
  const int l15 = lane & 15, l4 = lane >> 4;
  const size_t hoff = (size_t)bh * (S_LEN * HDIM);
  const u16s* Qb = Q + hoff;
  const u16s* Kb = K + hoff;
  const u16s* Vb = VT + hoff;   // [64][1024]
  u16s* Pw = Pl[wid];
  const int b = bh >> 4, h = bh & 15;

  const int kr = tid >> 3, kc = (tid & 7) * 8;   // K: row 0..31, col 0..56
  const int vr = tid >> 2, vc = (tid & 3) * 8;   // V: row 0..63, col 0..24

  for (int half = 0; half < 2; ++half) {
    const int qt = half ? (15 - p) : p;
    const int qrow = qt * 64 + wid * 16 + l15;
    const u16x8 qf0 = *(const u16x8*)(Qb + qrow * 64 + l4 * 8);
    const u16x8 qf1 = *(const u16x8*)(Qb + qrow * 64 + 32 + l4 * 8);
    f32x4 oa[4] = {};
    float mrun = -1e30f, lsum = 0.f;
    const int nkt = 2 * qt + 2;

    u16x8 kreg = *(const u16x8*)(Kb + (size_t)kr * 64 + kc);
    u16x8 vreg = *(const u16x8*)(Vb + (size_t)vr * 1024 + vc);

    for (int kt = 0; kt < nkt; ++kt) {
      __syncthreads();
      *(u16x8*)(Ks + kr * 72 + kc) = kreg;
      *(u16x8*)(Vs + vr * 40 + vc) = vreg;
      __syncthreads();
      if (kt + 1 < nkt) {
        kreg = *(const u16x8*)(Kb + (size_t)((kt + 1) * 32 + kr) * 64 + kc);
        vreg = *(const u16x8*)(Vb + (size_t)vr * 1024 + (kt + 1) * 32 + vc);
      }
      const int kbase = kt * 32;
      f32x4 sc0 = {0.f, 0.f, 0.f, 0.f}, sc1 = {0.f, 0.f, 0.f, 0.f};
      {
        u16x8 kf00 = *(const u16x8*)(Ks + l15 * 72 + l4 * 8);
        u16x8 kf01 = *(const u16x8*)(Ks + l15 * 72 + 32 + l4 * 8);
        u16x8 kf10 = *(const u16x8*)(Ks + (16 + l15) * 72 + l4 * 8);
        u16x8 kf11 = *(const u16x8*)(Ks + (16 + l15) * 72 + 32 + l4 * 8);
        __builtin_amdgcn_s_setprio(1);
        sc0 = mfma_bf16(kf00, qf0, sc0);
        sc0 = mfma_bf16(kf01, qf1, sc0);
        sc1 = mfma_bf16(kf10, qf0, sc1);
        sc1 = mfma_bf16(kf11, qf1, sc1);
        __builtin_amdgcn_s_setprio(0);
      }
      u16x8 vf[4];
#pragma unroll
      for (int df = 0; df < 4; ++df)
        vf[df] = *(const u16x8*)(Vs + (df * 16 + l15) * 40 + l4 * 8);

      float sv[8];
      float pmax = -1e30f;
#pragma unroll
      for (int r = 0; r < 4; ++r) {
        const int kg0 = kbase + l4 * 4 + r;
        const int kg1 = kbase + 16 + l4 * 4 + r;
        const float s0 = (kg0 <= qrow) ? sc0[r] : -1e9f;
        const float s1 = (kg1 <= qrow) ? sc1[r] : -1e9f;
        sv[r] = s0; sv[4 + r] = s1;
        pmax = fmaxf(pmax, fmaxf(s0, s1));
      }
      pmax = fmaxf(pmax, __shfl_xor(pmax, 16));
      pmax = fmaxf(pmax, __shfl_xor(pmax, 32));
      const float mnew = fmaxf(mrun, pmax);
      const float fsc = __expf(mrun - mnew);
      float psum = 0.f;
#pragma unroll
      for (int i = 0; i < 8; ++i) { float pv = __expf(sv[i] - mnew); sv[i] = pv; psum += pv; }
      psum += __shfl_xor(psum, 16);
      psum += __shfl_xor(psum, 32);
      lsum = lsum * fsc + psum;
      mrun = mnew;
#pragma unroll
      for (int df = 0; df < 4; ++df) oa[df] *= fsc;

      u16x4 pk0, pk1;
#pragma unroll
      for (int r = 0; r < 4; ++r) { pk0[r] = f2bf(sv[r]); pk1[r] = f2bf(sv[4 + r]); }
      *(u16x4*)(Pw + l15 * 40 + l4 * 4) = pk0;
      *(u16x4*)(Pw + l15 * 40 + 16 + l4 * 4) = pk1;
      asm volatile("s_waitcnt lgkmcnt(0)" ::: "memory");
      const u16x8 pf = *(const u16x8*)(Pw + l15 * 40 + l4 * 8);
      __builtin_amdgcn_s_setprio(1);
#pragma unroll
      for (int df = 0; df < 4; ++df)
        oa[df] = mfma_bf16(vf[df], pf, oa[df]);
      __builtin_amdgcn_s_setprio(0);
    }
    const float inv = 1.f / lsum;
    u16s* orow = O + ((size_t)qrow * 8 + b) * EMB + h * 64;
#pragma unroll
    for (int df = 0; df < 4; ++df)
#pragma unroll
      for (int r = 0; r < 4; ++r)
        orow[df * 16 + l4 * 4 + r] = f2bf(oa[df][r] * inv);
  }
}

// ---------------- driver ----------------
extern "C" void kernel_launch(void* const* d_in, const int* in_sizes, int n_in,
                              void* d_out, int out_size, void* d_ws, size_t ws_size,
                              hipStream_t stream) {
  const float* x = (const float*)d_in[0];
  const float* z = (const float*)d_in[1];
  const float* wq = (const float*)d_in[2];  const float* bq = (const float*)d_in[3];
  const float* wk = (const float*)d_in[4];  const float* bk = (const float*)d_in[5];
  const float* wv = (const float*)d_in[6];  const float* bv = (const float*)d_in[7];
  const float* wo = (const float*)d_in[8];  const float* bo = (const float*)d_in[9];
  const float* ln1g = (const float*)d_in[10]; const float* ln1b = (const float*)d_in[11];
  const float* pghw = (const float*)d_in[12]; const float* pghb = (const float*)d_in[13];
  const float* pgzw = (const float*)d_in[14]; const float* pgzb = (const float*)d_in[15];
  const float* pvw  = (const float*)d_in[16]; const float* pvb  = (const float*)d_in[17];
  const float* ln2g = (const float*)d_in[18]; const float* ln2b = (const float*)d_in[19];
  const float* fc1w = (const float*)d_in[20]; const float* fc1b = (const float*)d_in[21];
  const float* fc2w = (const float*)d_in[22]; const float* fc2b = (const float*)d_in[23];
  const float* ln3g = (const float*)d_in[24]; const float* ln3b = (const float*)d_in[25];

  char* ws = (char*)d_ws;
  size_t off = 0;
  auto alloc = [&](size_t bytes) -> char* {
    char* p = ws + off;
    off += (bytes + 255) & ~(size_t)255;
    return p;
  };

  u16s* bw_qkv = (u16s*)alloc(2u * 3145728);  // wq|wk|wv concat (3072x1024)
  u16s* bw_o = (u16s*)alloc(2u * 1048576);
  u16s* bw_g = (u16s*)alloc(2u * 1048576);
  u16s* bw_f1 = (u16s*)alloc(2u * 4194304);
  u16s* bw_f2 = (u16s*)alloc(2u * 4194304);
  u16s* xb = (u16s*)alloc(2u * 8388608);
  // qh, kh, vT, attnb are four contiguous 16MB buffers (the QKV3 epilogue
  // relies on qh+8388608 == kh, qh+16777216 == vT); hbuf (8192x4096 bf16 =
  // 64MB) aliases all four. vT is V pre-transposed per head: vT[bh][64][1024].
  u16s* qh = (u16s*)alloc(2u * 8388608);
  u16s* kh = (u16s*)alloc(2u * 8388608);
  u16s* vT = (u16s*)alloc(2u * 8388608);
  u16s* attnb = (u16s*)alloc(2u * 8388608);
  u16s* hbuf = qh;
  float* ybuf = (float*)alloc(4u * 8388608);
  u16s* x1b = (u16s*)alloc(2u * 8388608);
  float* x1f = (float*)alloc(4u * 8388608);
  float* zgb = (float*)alloc(4u * 8192);
  float* zvb = (float*)alloc(4u * 8192);
  float* bqkv = (float*)alloc(4u * 3072);
  (void)off; (void)ws_size; (void)in_sizes; (void)n_in; (void)out_size;
  (void)kh; (void)vT;

  auto cast = [&](const float* in, u16s* out, int n) {
    cast_kernel<<<n / 1024, 256, 0, stream>>>(in, out, n / 4);
  };
  cast(x, xb, 8388608);
  cast(wq, bw_qkv, 1048576);
  cast(wk, bw_qkv + 1048576, 1048576);
  cast(wv, bw_qkv + 2097152, 1048576);
  cast(wo, bw_o, 1048576);
  cast(pghw, bw_g, 1048576);
  cast(fc1w, bw_f1, 4194304);
  cast(fc2w, bw_f2, 4194304);
  concat_bias_kernel<<<12, 256, 0, stream>>>(bq, bk, bv, bqkv);

  // fused QKV projection (N=3072) with head-scatter epilogue
  gemm_nt<EPI_QKV3><<<dim3(64, 24), 256, 0, stream>>>(
      xb, bw_qkv, bqkv, qh, nullptr, nullptr, nullptr, NTOK, 3072, EMB, 0.125f);

  attn_kernel<<<dim3(8, 128), 256, 0, stream>>>(qh, kh, vT, attnb);

  // out-proj + residual(x) -> ybuf (f32), then LN1 -> x1 (bf16 + f32)
  gemm_nt<EPI_RES><<<dim3(64, 8), 256, 0, stream>>>(
      attnb, bw_o, bo, ybuf, x, nullptr, nullptr, NTOK, EMB, EMB, 1.f);
  ln_kernel<0><<<NTOK, 256, 0, stream>>>(ybuf, ln1g, ln1b, x1b, x1f);

  // gated fusion
  zproj_kernel<<<4, 256, 0, stream>>>(z, pgzw, pgzb, zgb);
  zproj_kernel<<<4, 256, 0, stream>>>(z, pvw, pvb, zvb);
  gemm_nt<EPI_GATE><<<dim3(64, 8), 256, 0, stream>>>(
      x1b, bw_g, pghb, ybuf, x1f, zgb, zvb, NTOK, EMB, EMB, 1.f);
  ln_kernel<0><<<NTOK, 256, 0, stream>>>(ybuf, ln2g, ln2b, x1b, x1f);  // x2 aliases x1

  // FFN
  gemm_nt<EPI_RELU><<<dim3(64, 32), 256, 0, stream>>>(
      x1b, bw_f1, fc1b, hbuf, nullptr, nullptr, nullptr, NTOK, FDIM, EMB, 1.f);
  gemm_nt<EPI_RES><<<dim3(64, 8), 256, 0, stream>>>(
      hbuf, bw_f2, fc2b, ybuf, x1f, nullptr, nullptr, NTOK, EMB, FDIM, 1.f);
  ln_kernel<1><<<NTOK, 256, 0, stream>>>(ybuf, ln3g, ln3b, nullptr, (float*)d_out);
}

// Round 7
// 592.123 us; speedup vs baseline: 1.5123x; 1.2390x over previous
//
#include <hip/hip_runtime.h>
#include <stdint.h>
#include <stddef.h>

#define S_LEN 1024
#define BATCH 8
#define EMB   1024
#define NHEAD 16
#define HDIM  64
#define FDIM  4096
#define NTOK  (S_LEN*BATCH)   // 8192

typedef unsigned short u16s;
typedef __attribute__((ext_vector_type(4))) float  f32x4;
typedef __attribute__((ext_vector_type(8))) u16s   u16x8;
typedef __attribute__((ext_vector_type(4))) u16s   u16x4;
typedef __attribute__((ext_vector_type(8))) __bf16 bf16x8;

__device__ __forceinline__ u16s f2bf(float f) {
  unsigned int x = __float_as_uint(f);
  return (u16s)((x + 0x7FFFu + ((x >> 16) & 1u)) >> 16);
}
__device__ __forceinline__ float bf2f(u16s u) {
  return __uint_as_float((unsigned int)u << 16);
}

__device__ __forceinline__ f32x4 mfma_bf16(u16x8 a, u16x8 b, f32x4 c) {
  return __builtin_amdgcn_mfma_f32_16x16x32_bf16(
      __builtin_bit_cast(bf16x8, a), __builtin_bit_cast(bf16x8, b), c, 0, 0, 0);
}

__device__ __forceinline__ void gload16(const void* g, void* l) {
  __builtin_amdgcn_global_load_lds(
      (const __attribute__((address_space(1))) unsigned int*)g,
      (__attribute__((address_space(3))) unsigned int*)l, 16, 0, 0);
}

// ---------------- cast fp32 -> bf16 ----------------
__global__ __launch_bounds__(256) void cast_kernel(const float* __restrict__ in,
                                                   u16s* __restrict__ out, int n4) {
  int i = blockIdx.x * 256 + threadIdx.x;
  if (i < n4) {
    float4 v = ((const float4*)in)[i];
    u16x4 o;
    o[0] = f2bf(v.x); o[1] = f2bf(v.y); o[2] = f2bf(v.z); o[3] = f2bf(v.w);
    ((u16x4*)out)[i] = o;
  }
}

// ---------------- concat q/k/v biases into one 3072 vector ----------------
__global__ __launch_bounds__(256) void concat_bias_kernel(const float* __restrict__ a,
                                                          const float* __restrict__ b,
                                                          const float* __restrict__ c,
                                                          float* __restrict__ o) {
  int i = blockIdx.x * 256 + threadIdx.x;  // 0..3071
  o[i] = (i < 1024) ? a[i] : (i < 2048) ? b[i - 1024] : c[i - 2048];
}

// ---------------- z projections (B=8 rows) ----------------
__global__ __launch_bounds__(256) void zproj_kernel(const float* __restrict__ z,
                                                    const float* __restrict__ w,
                                                    const float* __restrict__ bias,
                                                    float* __restrict__ out) {
  const int o = blockIdx.x * 256 + threadIdx.x;   // 0..1023
  float acc[8] = {};
  const float* wr = w + (size_t)o * EMB;
  for (int e = 0; e < EMB; e += 4) {
    float4 wv = *(const float4*)(wr + e);
#pragma unroll
    for (int b = 0; b < 8; ++b) {
      float4 zv = *(const float4*)(z + b * EMB + e);
      acc[b] += zv.x * wv.x + zv.y * wv.y + zv.z * wv.z + zv.w * wv.w;
    }
  }
  float bb = bias[o];
#pragma unroll
  for (int b = 0; b < 8; ++b) out[b * EMB + o] = acc[b] + bb;
}

// ---------------- LayerNorm (bf16 in) ----------------
// MODE 0: write bf16 ; MODE 1: write f32 (final output)
template <int MODE>
__global__ __launch_bounds__(256) void ln_kernel(const u16s* __restrict__ y,
                                                 const float* __restrict__ gam,
                                                 const float* __restrict__ bet,
                                                 u16s* __restrict__ obf,
                                                 float* __restrict__ of) {
  const int row = blockIdx.x;
  const int t = threadIdx.x;
  const u16s* yr = y + (size_t)row * EMB;
  u16x4 raw = ((const u16x4*)yr)[t];
  float4 v;
  v.x = bf2f(raw[0]); v.y = bf2f(raw[1]); v.z = bf2f(raw[2]); v.w = bf2f(raw[3]);
  float s = v.x + v.y + v.z + v.w;
  float s2 = v.x * v.x + v.y * v.y + v.z * v.z + v.w * v.w;
#pragma unroll
  for (int m = 1; m < 64; m <<= 1) { s += __shfl_xor(s, m); s2 += __shfl_xor(s2, m); }
  __shared__ float red[8];
  const int wid = t >> 6, lane = t & 63;
  if (lane == 0) { red[wid] = s; red[4 + wid] = s2; }
  __syncthreads();
  s = red[0] + red[1] + red[2] + red[3];
  s2 = red[4] + red[5] + red[6] + red[7];
  float mu = s * (1.f / EMB);
  float var = s2 * (1.f / EMB) - mu * mu;
  float rs = rsqrtf(var + 1e-5f);
  float4 g = ((const float4*)gam)[t];
  float4 b = ((const float4*)bet)[t];
  float4 o;
  o.x = (v.x - mu) * rs * g.x + b.x;
  o.y = (v.y - mu) * rs * g.y + b.y;
  o.z = (v.z - mu) * rs * g.z + b.z;
  o.w = (v.w - mu) * rs * g.w + b.w;
  if constexpr (MODE == 0) {
    u16x4 p;
    p[0] = f2bf(o.x); p[1] = f2bf(o.y); p[2] = f2bf(o.z); p[3] = f2bf(o.w);
    ((u16x4*)(obf + (size_t)row * EMB))[t] = p;
  } else {
    ((float4*)(of + (size_t)row * EMB))[t] = o;
  }
}

// ---------------- GEMM: C = A(MxK) * B(NxK)^T + bias, fused epilogues --------
// 128x128 tile, BK=64, 4 waves (2x2), each wave 4x4 frags of 16x16x32.
// LDS row-major [128][64] with XOR chunk swizzle (chunk c of row r at slot
// c^(r&7)): ds_read_b128 -> 2-way bank aliasing (free, R6: conflicts==0).
// Staging keeps global_load_lds with LINEAR LDS dest; XOR applied to the
// GLOBAL source chunk (both-sides rule); 8 lanes cover each row's contiguous
// 128B -> coalesced. Natural block order (R6's XCD swizzle caused 2.2x
// FETCH_SIZE: each XCD streamed full A through its 4MB L2 per bn-column).
// All inter-layer tensors are bf16 (residuals included) to cut f32 traffic.
enum { EPI_QKV3 = 0, EPI_RELU = 1, EPI_RES = 2, EPI_GATE = 3 };

template <int EPI>
__global__ __launch_bounds__(256, 4) void gemm_nt(const u16s* __restrict__ A,
                                                  const u16s* __restrict__ Bw,
                                                  const float* __restrict__ bias,
                                                  void* __restrict__ out,
                                                  const u16s* __restrict__ res,
                                                  const float* __restrict__ zg,
                                                  const float* __restrict__ zv,
                                                  int M, int N, int K, float scale) {
  __shared__ u16s As[128 * 64];
  __shared__ u16s Bs[128 * 64];
  const int tid = threadIdx.x;
  const int wid = tid >> 6, lane = tid & 63;
  const int wm = wid >> 1, wn = wid & 1;
  const int l15 = lane & 15, l4 = lane >> 4;
  const int bm0 = blockIdx.x * 128, bn0 = blockIdx.y * 128;

  const int wbase = tid & ~63;
  // per-thread staging source (linear LDS chunk ell = ii*256 + tid)
  int srowA[4], scolA[4];
#pragma unroll
  for (int ii = 0; ii < 4; ++ii) {
    const int ell = ii * 256 + tid;
    const int row = ell >> 3;
    srowA[ii] = row;
    scolA[ii] = ((ell & 7) ^ (row & 7)) * 8;
  }

  f32x4 acc[4][4] = {};
  const int nkt = K >> 6;
  for (int kt = 0; kt < nkt; ++kt) {
#pragma unroll
    for (int ii = 0; ii < 4; ++ii) {
      gload16(A + (size_t)(bm0 + srowA[ii]) * K + kt * 64 + scolA[ii],
              As + (size_t)(ii * 256 + wbase) * 8);
      gload16(Bw + (size_t)(bn0 + srowA[ii]) * K + kt * 64 + scolA[ii],
              Bs + (size_t)(ii * 256 + wbase) * 8);
    }
    __syncthreads();
#pragma unroll
    for (int kk = 0; kk < 2; ++kk) {
      const int cs = kk * 4 + l4;
      u16x8 af[4], bfr[4];
#pragma unroll
      for (int i = 0; i < 4; ++i) {
        const int row = wm * 64 + i * 16 + l15;
        af[i] = *(const u16x8*)(As + row * 64 + (cs ^ (l15 & 7)) * 8);
      }
#pragma unroll
      for (int j = 0; j < 4; ++j) {
        const int row = wn * 64 + j * 16 + l15;
        bfr[j] = *(const u16x8*)(Bs + row * 64 + (cs ^ (l15 & 7)) * 8);
      }
      __builtin_amdgcn_s_setprio(1);
#pragma unroll
      for (int i = 0; i < 4; ++i)
#pragma unroll
        for (int j = 0; j < 4; ++j)
          acc[i][j] = mfma_bf16(af[i], bfr[j], acc[i][j]);
      __builtin_amdgcn_s_setprio(0);
    }
    __syncthreads();
  }

  u16s* outb = (u16s*)out;
#pragma unroll
  for (int j = 0; j < 4; ++j) {
    const int gc = bn0 + wn * 64 + j * 16 + l15;
    const float bv = bias[gc];
#pragma unroll
    for (int i = 0; i < 4; ++i) {
      const int gr0 = bm0 + wm * 64 + i * 16 + l4 * 4;
#pragma unroll
      for (int r = 0; r < 4; ++r) {
        const int gr = gr0 + r;
        float v = acc[i][j][r] + bv;
        if constexpr (EPI == EPI_QKV3) {
          // columns 0..1023 -> Q (scaled), 1024..2047 -> K, 2048..3071 -> V^T
          const int which = gc >> 10, col = gc & 1023;
          const int srow = gr >> 3, b = gr & 7, h = col >> 6, d = col & 63;
          if (which == 0)
            outb[(size_t)(b * 16 + h) * 65536 + srow * 64 + d] = f2bf(v * scale);
          else if (which == 1)
            outb[8388608 + (size_t)(b * 16 + h) * 65536 + srow * 64 + d] = f2bf(v);
          else
            outb[16777216 + ((size_t)(b * 16 + h) * 64 + d) * 1024 + srow] = f2bf(v);
        } else if constexpr (EPI == EPI_RELU) {
          outb[(size_t)gr * N + gc] = f2bf(fmaxf(v, 0.f));
        } else if constexpr (EPI == EPI_RES) {
          outb[(size_t)gr * N + gc] = f2bf(v + bf2f(res[(size_t)gr * N + gc]));
        } else {  // EPI_GATE
          const float lin2 = v + zg[(gr & 7) * EMB + gc];
          const float gate = 1.f / (1.f + __expf(-lin2));
          outb[(size_t)gr * EMB + gc] =
              f2bf(bf2f(res[(size_t)gr * EMB + gc]) + gate * zv[(gr & 7) * EMB + gc]);
        }
      }
    }
  }
}

// ---------------- causal flash attention (LDS-staged, load-balanced) --------
__global__ __launch_bounds__(256) void attn_kernel(const u16s* __restrict__ Q,
                                                   const u16s* __restrict__ K,
                                                   const u16s* __restrict__ VT,
                                                   u16s* __restrict__ O) {
  __shared__ u16s Ks[32 * 72];
  __shared__ u16s Vs[64 * 40];
  __shared__ u16s Pl[4][16 * 40];
  const int p = blockIdx.x, bh = blockIdx.y;
  const int tid = threadIdx.x;
  const int wid = tid >> 6, lane = tid & 63;
  const int l15 = lane & 15, l4 = lane >> 4;
  const size_t hoff = (size_t)bh * (S_LEN * HDIM);
  const u16s* Qb = Q + hoff;
  const u16s* Kb = K + hoff;
  const u16s* Vb = VT + hoff;   // [64][1024]
  u16s* Pw = Pl[wid];
  const int b = bh >> 4, h = bh & 15;

  const int kr = tid >> 3, kc = (tid & 7) * 8;   // K: row 0..31, col 0..56
  const int vr = tid >> 2, vc = (tid & 3) * 8;   // V: row 0..63, col 0..24

  for (int half = 0; half < 2; ++half) {
    const int qt = half ? (15 - p) : p;
    const int qrow = qt * 64 + wid * 16 + l15;
    const u16x8 qf0 = *(const u16x8*)(Qb + qrow * 64 + l4 * 8);
    const u16x8 qf1 = *(const u16x8*)(Qb + qrow * 64 + 32 + l4 * 8);
    f32x4 oa[4] = {};
    float mrun = -1e30f, lsum = 0.f;
    const int nkt = 2 * qt + 2;

    u16x8 kreg = *(const u16x8*)(Kb + (size_t)kr * 64 + kc);
    u16x8 vreg = *(const u16x8*)(Vb + (size_t)vr * 1024 + vc);

    for (int kt = 0; kt < nkt; ++kt) {
      __syncthreads();
      *(u16x8*)(Ks + kr * 72 + kc) = kreg;
      *(u16x8*)(Vs + vr * 40 + vc) = vreg;
      __syncthreads();
      if (kt + 1 < nkt) {
        kreg = *(const u16x8*)(Kb + (size_t)((kt + 1) * 32 + kr) * 64 + kc);
        vreg = *(const u16x8*)(Vb + (size_t)vr * 1024 + (kt + 1) * 32 + vc);
      }
      const int kbase = kt * 32;
      f32x4 sc0 = {0.f, 0.f, 0.f, 0.f}, sc1 = {0.f, 0.f, 0.f, 0.f};
      {
        u16x8 kf00 = *(const u16x8*)(Ks + l15 * 72 + l4 * 8);
        u16x8 kf01 = *(const u16x8*)(Ks + l15 * 72 + 32 + l4 * 8);
        u16x8 kf10 = *(const u16x8*)(Ks + (16 + l15) * 72 + l4 * 8);
        u16x8 kf11 = *(const u16x8*)(Ks + (16 + l15) * 72 + 32 + l4 * 8);
        __builtin_amdgcn_s_setprio(1);
        sc0 = mfma_bf16(kf00, qf0, sc0);
        sc0 = mfma_bf16(kf01, qf1, sc0);
        sc1 = mfma_bf16(kf10, qf0, sc1);
        sc1 = mfma_bf16(kf11, qf1, sc1);
        __builtin_amdgcn_s_setprio(0);
      }
      u16x8 vf[4];
#pragma unroll
      for (int df = 0; df < 4; ++df)
        vf[df] = *(const u16x8*)(Vs + (df * 16 + l15) * 40 + l4 * 8);

      float sv[8];
      float pmax = -1e30f;
#pragma unroll
      for (int r = 0; r < 4; ++r) {
        const int kg0 = kbase + l4 * 4 + r;
        const int kg1 = kbase + 16 + l4 * 4 + r;
        const float s0 = (kg0 <= qrow) ? sc0[r] : -1e9f;
        const float s1 = (kg1 <= qrow) ? sc1[r] : -1e9f;
        sv[r] = s0; sv[4 + r] = s1;
        pmax = fmaxf(pmax, fmaxf(s0, s1));
      }
      pmax = fmaxf(pmax, __shfl_xor(pmax, 16));
      pmax = fmaxf(pmax, __shfl_xor(pmax, 32));
      const float mnew = fmaxf(mrun, pmax);
      const float fsc = __expf(mrun - mnew);
      float psum = 0.f;
#pragma unroll
      for (int i = 0; i < 8; ++i) { float pv = __expf(sv[i] - mnew); sv[i] = pv; psum += pv; }
      psum += __shfl_xor(psum, 16);
      psum += __shfl_xor(psum, 32);
      lsum = lsum * fsc + psum;
      mrun = mnew;
#pragma unroll
      for (int df = 0; df < 4; ++df) oa[df] *= fsc;

      u16x4 pk0, pk1;
#pragma unroll
      for (int r = 0; r < 4; ++r) { pk0[r] = f2bf(sv[r]); pk1[r] = f2bf(sv[4 + r]); }
      *(u16x4*)(Pw + l15 * 40 + l4 * 4) = pk0;
      *(u16x4*)(Pw + l15 * 40 + 16 + l4 * 4) = pk1;
      asm volatile("s_waitcnt lgkmcnt(0)" ::: "memory");
      const u16x8 pf = *(const u16x8*)(Pw + l15 * 40 + l4 * 8);
      __builtin_amdgcn_s_setprio(1);
#pragma unroll
      for (int df = 0; df < 4; ++df)
        oa[df] = mfma_bf16(vf[df], pf, oa[df]);
      __builtin_amdgcn_s_setprio(0);
    }
    const float inv = 1.f / lsum;
    u16s* orow = O + ((size_t)qrow * 8 + b) * EMB + h * 64;
#pragma unroll
    for (int df = 0; df < 4; ++df)
#pragma unroll
      for (int r = 0; r < 4; ++r)
        orow[df * 16 + l4 * 4 + r] = f2bf(oa[df][r] * inv);
  }
}

// ---------------- driver ----------------
extern "C" void kernel_launch(void* const* d_in, const int* in_sizes, int n_in,
                              void* d_out, int out_size, void* d_ws, size_t ws_size,
                              hipStream_t stream) {
  const float* x = (const float*)d_in[0];
  const float* z = (const float*)d_in[1];
  const float* wq = (const float*)d_in[2];  const float* bq = (const float*)d_in[3];
  const float* wk = (const float*)d_in[4];  const float* bk = (const float*)d_in[5];
  const float* wv = (const float*)d_in[6];  const float* bv = (const float*)d_in[7];
  const float* wo = (const float*)d_in[8];  const float* bo = (const float*)d_in[9];
  const float* ln1g = (const float*)d_in[10]; const float* ln1b = (const float*)d_in[11];
  const float* pghw = (const float*)d_in[12]; const float* pghb = (const float*)d_in[13];
  const float* pgzw = (const float*)d_in[14]; const float* pgzb = (const float*)d_in[15];
  const float* pvw  = (const float*)d_in[16]; const float* pvb  = (const float*)d_in[17];
  const float* ln2g = (const float*)d_in[18]; const float* ln2b = (const float*)d_in[19];
  const float* fc1w = (const float*)d_in[20]; const float* fc1b = (const float*)d_in[21];
  const float* fc2w = (const float*)d_in[22]; const float* fc2b = (const float*)d_in[23];
  const float* ln3g = (const float*)d_in[24]; const float* ln3b = (const float*)d_in[25];

  char* ws = (char*)d_ws;
  size_t off = 0;
  auto alloc = [&](size_t bytes) -> char* {
    char* p = ws + off;
    off += (bytes + 255) & ~(size_t)255;
    return p;
  };

  u16s* bw_qkv = (u16s*)alloc(2u * 3145728);  // wq|wk|wv concat (3072x1024)
  u16s* bw_o = (u16s*)alloc(2u * 1048576);
  u16s* bw_g = (u16s*)alloc(2u * 1048576);
  u16s* bw_f1 = (u16s*)alloc(2u * 4194304);
  u16s* bw_f2 = (u16s*)alloc(2u * 4194304);
  u16s* xb = (u16s*)alloc(2u * 8388608);
  // qh, kh, vT, attnb are four contiguous 16MB buffers (the QKV3 epilogue
  // relies on qh+8388608 == kh, qh+16777216 == vT); hbuf (8192x4096 bf16 =
  // 64MB) aliases all four. vT is V pre-transposed per head: vT[bh][64][1024].
  u16s* qh = (u16s*)alloc(2u * 8388608);
  u16s* kh = (u16s*)alloc(2u * 8388608);
  u16s* vT = (u16s*)alloc(2u * 8388608);
  u16s* attnb = (u16s*)alloc(2u * 8388608);
  u16s* hbuf = qh;
  u16s* ybufb = (u16s*)alloc(2u * 8388608);   // bf16 pre-LN buffer
  u16s* x1b = (u16s*)alloc(2u * 8388608);     // LN1 output (bf16)
  u16s* x2b = (u16s*)alloc(2u * 8388608);     // LN2 output (bf16)
  float* zgb = (float*)alloc(4u * 8192);
  float* zvb = (float*)alloc(4u * 8192);
  float* bqkv = (float*)alloc(4u * 3072);
  (void)off; (void)ws_size; (void)in_sizes; (void)n_in; (void)out_size;
  (void)kh; (void)vT;

  auto cast = [&](const float* in, u16s* out, int n) {
    cast_kernel<<<n / 1024, 256, 0, stream>>>(in, out, n / 4);
  };
  cast(x, xb, 8388608);
  cast(wq, bw_qkv, 1048576);
  cast(wk, bw_qkv + 1048576, 1048576);
  cast(wv, bw_qkv + 2097152, 1048576);
  cast(wo, bw_o, 1048576);
  cast(pghw, bw_g, 1048576);
  cast(fc1w, bw_f1, 4194304);
  cast(fc2w, bw_f2, 4194304);
  concat_bias_kernel<<<12, 256, 0, stream>>>(bq, bk, bv, bqkv);

  // fused QKV projection (N=3072) with head-scatter epilogue
  gemm_nt<EPI_QKV3><<<dim3(64, 24), 256, 0, stream>>>(
      xb, bw_qkv, bqkv, qh, nullptr, nullptr, nullptr, NTOK, 3072, EMB, 0.125f);

  attn_kernel<<<dim3(8, 128), 256, 0, stream>>>(qh, kh, vT, attnb);

  // out-proj + residual(xb) -> ybufb (bf16), then LN1 -> x1b
  gemm_nt<EPI_RES><<<dim3(64, 8), 256, 0, stream>>>(
      attnb, bw_o, bo, ybufb, xb, nullptr, nullptr, NTOK, EMB, EMB, 1.f);
  ln_kernel<0><<<NTOK, 256, 0, stream>>>(ybufb, ln1g, ln1b, x1b, nullptr);

  // gated fusion (residual x1b) -> ybufb, then LN2 -> x2b
  zproj_kernel<<<4, 256, 0, stream>>>(z, pgzw, pgzb, zgb);
  zproj_kernel<<<4, 256, 0, stream>>>(z, pvw, pvb, zvb);
  gemm_nt<EPI_GATE><<<dim3(64, 8), 256, 0, stream>>>(
      x1b, bw_g, pghb, ybufb, x1b, zgb, zvb, NTOK, EMB, EMB, 1.f);
  ln_kernel<0><<<NTOK, 256, 0, stream>>>(ybufb, ln2g, ln2b, x2b, nullptr);

  // FFN (residual x2b) -> ybufb, then LN3 -> d_out (f32)
  gemm_nt<EPI_RELU><<<dim3(64, 32), 256, 0, stream>>>(
      x2b, bw_f1, fc1b, hbuf, nullptr, nullptr, nullptr, NTOK, FDIM, EMB, 1.f);
  gemm_nt<EPI_RES><<<dim3(64, 8), 256, 0, stream>>>(
      hbuf, bw_f2, fc2b, ybufb, x2b, nullptr, nullptr, NTOK, EMB, FDIM, 1.f);
  ln_kernel<1><<<NTOK, 256, 0, stream>>>(ybufb, ln3g, ln3b, nullptr, (float*)d_out);
}